// Round 1
// baseline (69.202 us; speedup 1.0000x reference)
//
#include <hip/hip_runtime.h>

#define NPIX (512*512)
#define HH 512
#define WW 512
#define NIMG 32

__device__ __forceinline__ double wred(double v) {
#pragma unroll
    for (int off = 32; off; off >>= 1) v += __shfl_down(v, off, 64);
    return v;
}

struct G4 { double g[4]; };

__device__ __forceinline__ G4 load_gray(const float* __restrict__ x_img,
                                        const float* __restrict__ gray_img,
                                        size_t off) {
    G4 o;
    if (gray_img) {
        float4 f = *(const float4*)(gray_img + off);
        o.g[0] = f.x; o.g[1] = f.y; o.g[2] = f.z; o.g[3] = f.w;
    } else {
        float4 r = *(const float4*)(x_img + off);
        float4 g = *(const float4*)(x_img + NPIX + off);
        float4 b = *(const float4*)(x_img + 2 * NPIX + off);
        o.g[0] = 0.299 * (double)r.x + 0.587 * (double)g.x + 0.114 * (double)b.x;
        o.g[1] = 0.299 * (double)r.y + 0.587 * (double)g.y + 0.114 * (double)b.y;
        o.g[2] = 0.299 * (double)r.z + 0.587 * (double)g.z + 0.114 * (double)b.z;
        o.g[3] = 0.299 * (double)r.w + 0.587 * (double)g.w + 0.114 * (double)b.w;
    }
    return o;
}

// K1: gray conversion (+optional fp32 cache), partial {sum g, sum g^2}
__global__ __launch_bounds__(256) void k1(const float* __restrict__ x,
                                          double* __restrict__ p1,
                                          float* __restrict__ gray,
                                          int nchunks) {
    int img = blockIdx.x / nchunks;
    int chunk = blockIdx.x - img * nchunks;
    int iters = 256 / nchunks;
    size_t cb = (size_t)chunk * (NPIX / nchunks);
    const float* xr = x + (size_t)img * 3 * NPIX;
    float* gr = gray ? gray + (size_t)img * NPIX : nullptr;
    double sg = 0.0, sg2 = 0.0;
    for (int j = 0; j < iters; ++j) {
        size_t off = cb + ((size_t)j * 256 + threadIdx.x) * 4;
        float4 r = *(const float4*)(xr + off);
        float4 g = *(const float4*)(xr + NPIX + off);
        float4 b = *(const float4*)(xr + 2 * NPIX + off);
        double g0 = 0.299 * (double)r.x + 0.587 * (double)g.x + 0.114 * (double)b.x;
        double g1 = 0.299 * (double)r.y + 0.587 * (double)g.y + 0.114 * (double)b.y;
        double g2 = 0.299 * (double)r.z + 0.587 * (double)g.z + 0.114 * (double)b.z;
        double g3 = 0.299 * (double)r.w + 0.587 * (double)g.w + 0.114 * (double)b.w;
        sg += (g0 + g1) + (g2 + g3);
        sg2 += (g0 * g0 + g1 * g1) + (g2 * g2 + g3 * g3);
        if (gr) {
            float4 o = make_float4((float)g0, (float)g1, (float)g2, (float)g3);
            *(float4*)(gr + off) = o;
        }
    }
    __shared__ double lds[4][2];
    int lane = threadIdx.x & 63, wv = threadIdx.x >> 6;
    double acc[2] = {sg, sg2};
#pragma unroll
    for (int a = 0; a < 2; ++a) {
        double v = wred(acc[a]);
        if (lane == 0) lds[wv][a] = v;
    }
    __syncthreads();
    if (threadIdx.x < 2)
        p1[((size_t)img * nchunks + chunk) * 2 + threadIdx.x] =
            lds[0][threadIdx.x] + lds[1][threadIdx.x] + lds[2][threadIdx.x] + lds[3][threadIdx.x];
}

// K2: partial {sum a, sum a*y, sum a*x} with a = |g - mean|
__global__ __launch_bounds__(256) void k2(const float* __restrict__ x,
                                          const float* __restrict__ gray,
                                          const double* __restrict__ p1,
                                          double* __restrict__ p2,
                                          int nchunks) {
    int img = blockIdx.x / nchunks;
    int chunk = blockIdx.x - img * nchunks;
    __shared__ double bc[1];
    int lane = threadIdx.x & 63, wv = threadIdx.x >> 6;
    if (wv == 0) {
        double sg = 0.0;
        for (int c = lane; c < nchunks; c += 64)
            sg += p1[((size_t)img * nchunks + c) * 2 + 0];
        sg = wred(sg);
        if (lane == 0) bc[0] = sg / (double)NPIX;
    }
    __syncthreads();
    double mean = bc[0];

    int iters = 256 / nchunks;
    size_t cb = (size_t)chunk * (NPIX / nchunks);
    const float* xr = x + (size_t)img * 3 * NPIX;
    const float* gr = gray ? gray + (size_t)img * NPIX : nullptr;
    double sa = 0.0, say = 0.0, sax = 0.0;
    for (int j = 0; j < iters; ++j) {
        size_t off = cb + ((size_t)j * 256 + threadIdx.x) * 4;
        G4 gv = load_gray(xr, gr, off);
        double yi = (double)(int)(off >> 9);
        double xi0 = (double)(int)(off & 511);
#pragma unroll
        for (int u = 0; u < 4; ++u) {
            double a = fabs(gv.g[u] - mean);
            sa += a;
            say += a * yi;
            sax += a * (xi0 + (double)u);
        }
    }
    __shared__ double lds[4][3];
    double acc[3] = {sa, say, sax};
#pragma unroll
    for (int a = 0; a < 3; ++a) {
        double v = wred(acc[a]);
        if (lane == 0) lds[wv][a] = v;
    }
    __syncthreads();
    if (threadIdx.x < 3)
        p2[((size_t)img * nchunks + chunk) * 3 + threadIdx.x] =
            lds[0][threadIdx.x] + lds[1][threadIdx.x] + lds[2][threadIdx.x] + lds[3][threadIdx.x];
}

// K3: partial moment accumulators (10 per image)
__global__ __launch_bounds__(256) void k3(const float* __restrict__ x,
                                          const float* __restrict__ gray,
                                          const double* __restrict__ p1,
                                          const double* __restrict__ p2,
                                          double* __restrict__ p3,
                                          int nchunks) {
    int img = blockIdx.x / nchunks;
    int chunk = blockIdx.x - img * nchunks;
    __shared__ double bc[5];
    int lane = threadIdx.x & 63, wv = threadIdx.x >> 6;
    if (wv == 0) {
        double sg = 0, sg2 = 0, sa = 0, say = 0, sax = 0;
        for (int c = lane; c < nchunks; c += 64) {
            size_t b1 = (size_t)img * nchunks + c;
            sg += p1[b1 * 2]; sg2 += p1[b1 * 2 + 1];
            sa += p2[b1 * 3]; say += p2[b1 * 3 + 1]; sax += p2[b1 * 3 + 2];
        }
        sg = wred(sg); sg2 = wred(sg2);
        sa = wred(sa); say = wred(say); sax = wred(sax);
        if (lane == 0) {
            double mean = sg / (double)NPIX;
            double var = sg2 / (double)NPIX - mean * mean;
            if (var < 0.0) var = 0.0;
            double stdv = sqrt(var);
            double inv_stdeps = 1.0 / (stdv + 1e-8);
            double s = sa * inv_stdeps;
            double cy, cx;
            if (s < 1e-8) { cy = HH / 2.0; cx = WW / 2.0; }
            else { cy = say / sa; cx = sax / sa; }
            double dx2 = fmax(cx * cx, ((double)(WW - 1) - cx) * ((double)(WW - 1) - cx));
            double dy2 = fmax(cy * cy, ((double)(HH - 1) - cy) * ((double)(HH - 1) - cy));
            double max_r = sqrt(dx2 + dy2) + 1e-8;
            bc[0] = mean; bc[1] = inv_stdeps; bc[2] = cx; bc[3] = cy; bc[4] = 1.0 / max_r;
        }
    }
    __syncthreads();
    double mean = bc[0], inv_stdeps = bc[1], cx = bc[2], cy = bc[3], inv_maxr = bc[4];

    int iters = 256 / nchunks;
    size_t cb = (size_t)chunk * (NPIX / nchunks);
    const float* xr = x + (size_t)img * 3 * NPIX;
    const float* gr = gray ? gray + (size_t)img * NPIX : nullptr;
    double acc[10];
#pragma unroll
    for (int a = 0; a < 10; ++a) acc[a] = 0.0;

    for (int j = 0; j < iters; ++j) {
        size_t off = cb + ((size_t)j * 256 + threadIdx.x) * 4;
        G4 gv = load_gray(xr, gr, off);
        double dy = (double)(int)(off >> 9) - cy;
        double xi0 = (double)(int)(off & 511);
#pragma unroll
        for (int u = 0; u < 4; ++u) {
            double w = (gv.g[u] - mean) * inv_stdeps;
            double dx = (xi0 + (double)u) - cx;
            double r2 = dx * dx + dy * dy;
            double rr = sqrt(r2 + 1e-20) * inv_maxr;
            rr = fmin(rr, 1.0);
            double c1, s1;
            if (r2 > 0.0) {
                double inv_rho = 1.0 / sqrt(r2);
                c1 = dx * inv_rho; s1 = dy * inv_rho;
            } else { c1 = 1.0; s1 = 0.0; }
            double c2 = c1 * c1 - s1 * s1, s2 = 2.0 * c1 * s1;
            double c3 = c2 * c1 - s2 * s1, s3 = s2 * c1 + c2 * s1;
            double rp2 = rr * rr, rp3 = rp2 * rr;
            double w1 = rr * w, w2 = rp2 * w, w3 = rp3 * w;
            acc[0] += w;
            acc[1] += w2;
            acc[2] += w1 * c1; acc[3] += w1 * s1;
            acc[4] += w2 * c2; acc[5] += w2 * s2;
            acc[6] += w3 * c3; acc[7] += w3 * s3;
            acc[8] += w3 * c1; acc[9] += w3 * s1;
        }
    }
    __shared__ double lds[4][10];
#pragma unroll
    for (int a = 0; a < 10; ++a) {
        double v = wred(acc[a]);
        if (lane == 0) lds[wv][a] = v;
    }
    __syncthreads();
    if (threadIdx.x < 10)
        p3[((size_t)img * nchunks + chunk) * 10 + threadIdx.x] =
            lds[0][threadIdx.x] + lds[1][threadIdx.x] + lds[2][threadIdx.x] + lds[3][threadIdx.x];
}

// K4: finalize 32x20 outputs (one wave per image)
__global__ __launch_bounds__(64) void k4(const double* __restrict__ p1,
                                         const double* __restrict__ p2,
                                         const double* __restrict__ p3,
                                         float* __restrict__ out,
                                         int nchunks) {
    int img = blockIdx.x;
    int lane = threadIdx.x;
    double sg = 0, sg2 = 0, sa = 0, say = 0, sax = 0;
    double m[10];
#pragma unroll
    for (int a = 0; a < 10; ++a) m[a] = 0.0;
    for (int c = lane; c < nchunks; c += 64) {
        size_t b = (size_t)img * nchunks + c;
        sg += p1[b * 2]; sg2 += p1[b * 2 + 1];
        sa += p2[b * 3]; say += p2[b * 3 + 1]; sax += p2[b * 3 + 2];
#pragma unroll
        for (int a = 0; a < 10; ++a) m[a] += p3[b * 10 + a];
    }
    sg = wred(sg); sg2 = wred(sg2);
    sa = wred(sa); say = wred(say); sax = wred(sax);
#pragma unroll
    for (int a = 0; a < 10; ++a) m[a] = wred(m[a]);
    if (lane == 0) {
        double mean = sg / (double)NPIX;
        double var = sg2 / (double)NPIX - mean * mean;
        if (var < 0.0) var = 0.0;
        double stdv = sqrt(var);
        double inv_stdeps = 1.0 / (stdv + 1e-8);
        double s = sa * inv_stdeps;
        double cy, cx;
        if (s < 1e-8) { cy = HH / 2.0; cx = WW / 2.0; }
        else { cy = say / sa; cx = sax / sa; }
        double dx2 = fmax(cx * cx, ((double)(WW - 1) - cx) * ((double)(WW - 1) - cx));
        double dy2 = fmax(cy * cy, ((double)(HH - 1) - cy) * ((double)(HH - 1) - cy));
        double max_r = sqrt(dx2 + dy2) + 1e-8;
        double inv_denom = 1.0 / (max_r * max_r + 1e-8);
        double S0 = m[0], S2 = m[1], C1 = m[2], S1v = m[3], C2 = m[4], Sm2 = m[5];
        double C3 = m[6], Sm3 = m[7], C31 = m[8], S31 = m[9];
        double f0 = fabs(S0) * inv_denom;
        double f1 = sqrt(C1 * C1 + S1v * S1v) * inv_denom;
        double f3 = sqrt(C2 * C2 + Sm2 * Sm2) * inv_denom;
        double f4 = fabs(2.0 * S2 - S0) * inv_denom;
        double f6 = sqrt(C3 * C3 + Sm3 * Sm3) * inv_denom;
        double a31r = 3.0 * C31 - 2.0 * C1, a31i = 3.0 * S31 - 2.0 * S1v;
        double f7 = sqrt(a31r * a31r + a31i * a31i) * inv_denom;
        float* o = out + (size_t)img * 20;
        o[0] = (float)f0;
        o[1] = (float)f1; o[2] = (float)f1;
        o[3] = (float)f3; o[4] = (float)f4; o[5] = (float)f3;
        o[6] = (float)f6; o[7] = (float)f7; o[8] = (float)f7; o[9] = (float)f6;
        for (int k = 10; k < 20; ++k) o[k] = 0.0f;
    }
}

extern "C" void kernel_launch(void* const* d_in, const int* in_sizes, int n_in,
                              void* d_out, int out_size, void* d_ws, size_t ws_size,
                              hipStream_t stream) {
    const float* x = (const float*)d_in[0];
    float* out = (float*)d_out;

    int nchunks = 64;
    while (nchunks > 1 && (size_t)NIMG * nchunks * 15 * sizeof(double) > ws_size)
        nchunks >>= 1;

    double* p1 = (double*)d_ws;
    double* p2 = p1 + (size_t)NIMG * nchunks * 2;
    double* p3 = p2 + (size_t)NIMG * nchunks * 3;
    size_t base = (size_t)NIMG * nchunks * 15 * sizeof(double);
    base = (base + 255) & ~(size_t)255;

    float* gray = nullptr;
    if (ws_size >= base + (size_t)NIMG * NPIX * sizeof(float))
        gray = (float*)((char*)d_ws + base);

    dim3 grid(NIMG * nchunks);
    k1<<<grid, 256, 0, stream>>>(x, p1, gray, nchunks);
    k2<<<grid, 256, 0, stream>>>(x, gray, p1, p2, nchunks);
    k3<<<grid, 256, 0, stream>>>(x, gray, p1, p2, p3, nchunks);
    k4<<<NIMG, 64, 0, stream>>>(p1, p2, p3, out, nchunks);
}

// Round 2
// 47.879 us; speedup vs baseline: 1.4454x; 1.4454x over previous
//
#include <hip/hip_runtime.h>

#define NPIX (512*512)
#define HH 512
#define WW 512
#define NIMG 32
#define CTR 255.5f

__device__ __forceinline__ double wredd(double v) {
#pragma unroll
    for (int off = 32; off; off >>= 1) v += __shfl_down(v, off, 64);
    return v;
}

struct F4 { float g[4]; };

__device__ __forceinline__ F4 load_gray4(const float* __restrict__ xr,
                                         const float* __restrict__ gr,
                                         size_t off) {
    F4 o;
    if (gr) {
        float4 f = *(const float4*)(gr + off);
        o.g[0] = f.x; o.g[1] = f.y; o.g[2] = f.z; o.g[3] = f.w;
    } else {
        float4 r = *(const float4*)(xr + off);
        float4 g = *(const float4*)(xr + NPIX + off);
        float4 b = *(const float4*)(xr + 2 * NPIX + off);
        o.g[0] = 0.299f * r.x + 0.587f * g.x + 0.114f * b.x;
        o.g[1] = 0.299f * r.y + 0.587f * g.y + 0.114f * b.y;
        o.g[2] = 0.299f * r.z + 0.587f * g.z + 0.114f * b.z;
        o.g[3] = 0.299f * r.w + 0.587f * g.w + 0.114f * b.w;
    }
    return o;
}

// K1: one pass over x. gray conversion (+fp32 cache) and 11 partials per chunk:
// {Sg, Sg2, G10, G01, G20, G11, G02, G30, G21, G12, G03} with centered coords
// u0 = x-255.5, v0 = y-255.5. Raw moments need neither mean nor COM.
#define NP1 12
__global__ __launch_bounds__(256) void k1(const float* __restrict__ x,
                                          double* __restrict__ p1,
                                          float* __restrict__ gray,
                                          int nchunks) {
    int img = blockIdx.x / nchunks;
    int chunk = blockIdx.x - img * nchunks;
    int iters = 256 / nchunks;
    size_t cb = (size_t)chunk * (NPIX / nchunks);
    const float* xr = x + (size_t)img * 3 * NPIX;
    float* gr = gray ? gray + (size_t)img * NPIX : nullptr;

    float A[11];
#pragma unroll
    for (int a = 0; a < 11; ++a) A[a] = 0.0f;

    for (int j = 0; j < iters; ++j) {
        size_t off = cb + ((size_t)j * 256 + threadIdx.x) * 4;
        float4 r = *(const float4*)(xr + off);
        float4 g = *(const float4*)(xr + NPIX + off);
        float4 b = *(const float4*)(xr + 2 * NPIX + off);
        float gv[4];
        gv[0] = 0.299f * r.x + 0.587f * g.x + 0.114f * b.x;
        gv[1] = 0.299f * r.y + 0.587f * g.y + 0.114f * b.y;
        gv[2] = 0.299f * r.z + 0.587f * g.z + 0.114f * b.z;
        gv[3] = 0.299f * r.w + 0.587f * g.w + 0.114f * b.w;
        if (gr) *(float4*)(gr + off) = make_float4(gv[0], gv[1], gv[2], gv[3]);

        float v = (float)(int)(off >> 9) - CTR;
        float v2 = v * v, v3 = v2 * v;
        float u0 = (float)(int)(off & 511) - CTR;
#pragma unroll
        for (int u = 0; u < 4; ++u) {
            float gg = gv[u];
            float uu = u0 + (float)u;
            float t1 = gg * uu, t2 = t1 * uu, t3 = t2 * uu;
            A[0] += gg;            // Sg  (= G00)
            A[1] += gg * gg;       // Sg2
            A[2] += t1;            // G10
            A[3] += gg * v;        // G01
            A[4] += t2;            // G20
            A[5] += t1 * v;       // G11
            A[6] += gg * v2;       // G02
            A[7] += t3;            // G30
            A[8] += t2 * v;       // G21
            A[9] += t1 * v2;      // G12
            A[10] += gg * v3;      // G03
        }
    }

    __shared__ double lds[4][11];
    int lane = threadIdx.x & 63, wv = threadIdx.x >> 6;
#pragma unroll
    for (int a = 0; a < 11; ++a) {
        double s = wredd((double)A[a]);
        if (lane == 0) lds[wv][a] = s;
    }
    __syncthreads();
    if (threadIdx.x < 11)
        p1[((size_t)img * nchunks + chunk) * NP1 + threadIdx.x] =
            lds[0][threadIdx.x] + lds[1][threadIdx.x] + lds[2][threadIdx.x] + lds[3][threadIdx.x];
}

// K2: second pass (gray is L2/L3-hot): partial {Sa, Sa*u0, Sa*v0}, a = |g - mean|
__global__ __launch_bounds__(256) void k2(const float* __restrict__ x,
                                          const float* __restrict__ gray,
                                          const double* __restrict__ p1,
                                          double* __restrict__ p2,
                                          int nchunks) {
    int img = blockIdx.x / nchunks;
    int chunk = blockIdx.x - img * nchunks;
    __shared__ double bmean;
    int lane = threadIdx.x & 63, wv = threadIdx.x >> 6;
    if (wv == 0) {
        double sg = 0.0;
        for (int c = lane; c < nchunks; c += 64)
            sg += p1[((size_t)img * nchunks + c) * NP1 + 0];
        sg = wredd(sg);
        if (lane == 0) bmean = sg / (double)NPIX;
    }
    __syncthreads();
    float mean = (float)bmean;

    int iters = 256 / nchunks;
    size_t cb = (size_t)chunk * (NPIX / nchunks);
    const float* xr = x + (size_t)img * 3 * NPIX;
    const float* gr = gray ? gray + (size_t)img * NPIX : nullptr;
    float sa = 0.0f, sax = 0.0f, say = 0.0f;
    for (int j = 0; j < iters; ++j) {
        size_t off = cb + ((size_t)j * 256 + threadIdx.x) * 4;
        F4 gv = load_gray4(xr, gr, off);
        float v = (float)(int)(off >> 9) - CTR;
        float u0 = (float)(int)(off & 511) - CTR;
#pragma unroll
        for (int u = 0; u < 4; ++u) {
            float a = fabsf(gv.g[u] - mean);
            sa += a;
            sax += a * (u0 + (float)u);
            say += a * v;
        }
    }
    __shared__ double lds[4][3];
    float acc[3] = {sa, sax, say};
#pragma unroll
    for (int a = 0; a < 3; ++a) {
        double s = wredd((double)acc[a]);
        if (lane == 0) lds[wv][a] = s;
    }
    __syncthreads();
    if (threadIdx.x < 3)
        p2[((size_t)img * nchunks + chunk) * 3 + threadIdx.x] =
            lds[0][threadIdx.x] + lds[1][threadIdx.x] + lds[2][threadIdx.x] + lds[3][threadIdx.x];
}

// K3: finalize. One block (64 threads) per image. Binomial-shift raw moments to
// the COM, apply inv_std / inv_maxr powers, emit 20 floats.
__global__ __launch_bounds__(64) void k3f(const double* __restrict__ p1,
                                          const double* __restrict__ p2,
                                          float* __restrict__ out,
                                          int nchunks) {
    int img = blockIdx.x;
    int lane = threadIdx.x;
    double M[11], B[3];
#pragma unroll
    for (int a = 0; a < 11; ++a) M[a] = 0.0;
#pragma unroll
    for (int a = 0; a < 3; ++a) B[a] = 0.0;
    for (int c = lane; c < nchunks; c += 64) {
        size_t b = (size_t)img * nchunks + c;
#pragma unroll
        for (int a = 0; a < 11; ++a) M[a] += p1[b * NP1 + a];
#pragma unroll
        for (int a = 0; a < 3; ++a) B[a] += p2[b * 3 + a];
    }
#pragma unroll
    for (int a = 0; a < 11; ++a) M[a] = wredd(M[a]);
#pragma unroll
    for (int a = 0; a < 3; ++a) B[a] = wredd(B[a]);

    if (lane == 0) {
        const double N = (double)NPIX;
        double G00 = M[0], Sg2 = M[1];
        double G10 = M[2], G01 = M[3], G20 = M[4], G11 = M[5], G02 = M[6];
        double G30 = M[7], G21 = M[8], G12 = M[9], G03 = M[10];
        double A0 = B[0], Ax = B[1], Ay = B[2];

        double mean = G00 / N;
        double var = Sg2 / N - mean * mean;
        if (var < 0.0) var = 0.0;
        double inv_std = 1.0 / (sqrt(var) + 1e-8);

        double s_chk = A0 * inv_std;
        double dxc, dyc;  // cx-255.5, cy-255.5
        if (s_chk < 1e-8) { dxc = 0.5; dyc = 0.5; }  // cx = W/2 = 256.0
        else { dxc = Ax / A0; dyc = Ay / A0; }

        // grid-sum constants (centered coords): odd powers vanish
        double S2 = 512.0 * (512.0 * 512.0 - 1.0) / 12.0;
        double P00 = N, P20 = S2 * 512.0, P02 = S2 * 512.0;

        double W00 = G00 - mean * P00;
        double W10 = G10, W01 = G01;
        double W20 = G20 - mean * P20;
        double W11 = G11;
        double W02 = G02 - mean * P02;
        double W30 = G30, W21 = G21, W12 = G12, W03 = G03;

        double dx = dxc, dy = dyc;
        double N00 = W00;
        double N10 = W10 - dx * W00;
        double N01 = W01 - dy * W00;
        double N20 = W20 - 2.0 * dx * W10 + dx * dx * W00;
        double N11 = W11 - dx * W01 - dy * W10 + dx * dy * W00;
        double N02 = W02 - 2.0 * dy * W01 + dy * dy * W00;
        double N30 = W30 - 3.0 * dx * W20 + 3.0 * dx * dx * W10 - dx * dx * dx * W00;
        double N21 = W21 - dy * W20 - 2.0 * dx * W11 + 2.0 * dx * dy * W10
                   + dx * dx * W01 - dx * dx * dy * W00;
        double N12 = W12 - dx * W02 - 2.0 * dy * W11 + 2.0 * dx * dy * W01
                   + dy * dy * W10 - dx * dy * dy * W00;
        double N03 = W03 - 3.0 * dy * W02 + 3.0 * dy * dy * W01 - dy * dy * dy * W00;

        // max_r at a corner: per-axis max distance
        double cx = CTR + dx, cy = CTR + dy;
        double mdx = fmax(cx, 511.0 - cx), mdy = fmax(cy, 511.0 - cy);
        double max_r = sqrt(mdx * mdx + mdy * mdy) + 1e-8;
        double imr = 1.0 / max_r;
        double im1 = inv_std * imr, im2 = im1 * imr, im3 = im2 * imr;
        double inv_denom = 1.0 / (max_r * max_r + 1e-8);

        double S0 = N00 * inv_std;
        double R2 = (N20 + N02) * im2;                // sum w r^2/maxr^2
        double C1 = N10 * im1, S1 = N01 * im1;
        double C2 = (N20 - N02) * im2, Sm2 = 2.0 * N11 * im2;
        double C3 = (N30 - 3.0 * N12) * im3, Sm3 = (3.0 * N21 - N03) * im3;
        double C31 = (N30 + N12) * im3, S31 = (N21 + N03) * im3;

        double f0 = fabs(S0) * inv_denom;
        double f1 = sqrt(C1 * C1 + S1 * S1) * inv_denom;
        double f3 = sqrt(C2 * C2 + Sm2 * Sm2) * inv_denom;
        double f4 = fabs(2.0 * R2 - S0) * inv_denom;
        double f6 = sqrt(C3 * C3 + Sm3 * Sm3) * inv_denom;
        double a31r = 3.0 * C31 - 2.0 * C1, a31i = 3.0 * S31 - 2.0 * S1;
        double f7 = sqrt(a31r * a31r + a31i * a31i) * inv_denom;

        float* o = out + (size_t)img * 20;
        o[0] = (float)f0;
        o[1] = (float)f1; o[2] = (float)f1;
        o[3] = (float)f3; o[4] = (float)f4; o[5] = (float)f3;
        o[6] = (float)f6; o[7] = (float)f7; o[8] = (float)f7; o[9] = (float)f6;
        for (int k = 10; k < 20; ++k) o[k] = 0.0f;
    }
}

extern "C" void kernel_launch(void* const* d_in, const int* in_sizes, int n_in,
                              void* d_out, int out_size, void* d_ws, size_t ws_size,
                              hipStream_t stream) {
    const float* x = (const float*)d_in[0];
    float* out = (float*)d_out;

    int nchunks = 64;
    while (nchunks > 1 && (size_t)NIMG * nchunks * (NP1 + 3) * sizeof(double) > ws_size)
        nchunks >>= 1;

    double* p1 = (double*)d_ws;
    double* p2 = p1 + (size_t)NIMG * nchunks * NP1;
    size_t base = (size_t)NIMG * nchunks * (NP1 + 3) * sizeof(double);
    base = (base + 255) & ~(size_t)255;

    float* gray = nullptr;
    if (ws_size >= base + (size_t)NIMG * NPIX * sizeof(float))
        gray = (float*)((char*)d_ws + base);

    dim3 grid(NIMG * nchunks);
    k1<<<grid, 256, 0, stream>>>(x, p1, gray, nchunks);
    k2<<<grid, 256, 0, stream>>>(x, gray, p1, p2, nchunks);
    k3f<<<NIMG, 64, 0, stream>>>(p1, p2, out, nchunks);
}

// Round 3
// 46.349 us; speedup vs baseline: 1.4931x; 1.0330x over previous
//
#include <hip/hip_runtime.h>

#define NPIX (512*512)
#define HH 512
#define WW 512
#define NIMG 32
#define CTR 255.5f
#define NCH 32          // chunks per image
#define NP1 12

__device__ __forceinline__ double wredd(double v) {
#pragma unroll
    for (int off = 32; off; off >>= 1) v += __shfl_down(v, off, 64);
    return v;
}

__device__ __forceinline__ void gray4(const float* __restrict__ xr, size_t off,
                                      float gv[4]) {
    float4 r = *(const float4*)(xr + off);
    float4 g = *(const float4*)(xr + NPIX + off);
    float4 b = *(const float4*)(xr + 2 * NPIX + off);
    gv[0] = 0.299f * r.x + 0.587f * g.x + 0.114f * b.x;
    gv[1] = 0.299f * r.y + 0.587f * g.y + 0.114f * b.y;
    gv[2] = 0.299f * r.z + 0.587f * g.z + 0.114f * b.z;
    gv[3] = 0.299f * r.w + 0.587f * g.w + 0.114f * b.w;
}

// K1: one pass over x. 11 partials per (img, chunk):
// {Sg, Sg2, G10, G01, G20, G11, G02, G30, G21, G12, G03}, coords centered at 255.5.
__global__ __launch_bounds__(256) void k1(const float* __restrict__ x,
                                          double* __restrict__ p1) {
    int img = blockIdx.x >> 5;          // / NCH
    int chunk = blockIdx.x & (NCH - 1);
    const int iters = NPIX / NCH / 1024;  // 8
    size_t cb = (size_t)chunk * (NPIX / NCH);
    const float* xr = x + (size_t)img * 3 * NPIX;

    float A[11];
#pragma unroll
    for (int a = 0; a < 11; ++a) A[a] = 0.0f;

    for (int j = 0; j < iters; ++j) {
        size_t off = cb + ((size_t)j * 256 + threadIdx.x) * 4;
        float gv[4];
        gray4(xr, off, gv);
        float v = (float)(int)(off >> 9) - CTR;
        float v2 = v * v, v3 = v2 * v;
        float u0 = (float)(int)(off & 511) - CTR;
#pragma unroll
        for (int u = 0; u < 4; ++u) {
            float gg = gv[u];
            float uu = u0 + (float)u;
            float t1 = gg * uu, t2 = t1 * uu, t3 = t2 * uu;
            A[0] += gg;
            A[1] += gg * gg;
            A[2] += t1;
            A[3] += gg * v;
            A[4] += t2;
            A[5] += t1 * v;
            A[6] += gg * v2;
            A[7] += t3;
            A[8] += t2 * v;
            A[9] += t1 * v2;
            A[10] += gg * v3;
        }
    }

    __shared__ double lds[4][11];
    int lane = threadIdx.x & 63, wv = threadIdx.x >> 6;
#pragma unroll
    for (int a = 0; a < 11; ++a) {
        double s = wredd((double)A[a]);
        if (lane == 0) lds[wv][a] = s;
    }
    __syncthreads();
    if (threadIdx.x < 11)
        p1[((size_t)img * NCH + chunk) * NP1 + threadIdx.x] =
            lds[0][threadIdx.x] + lds[1][threadIdx.x] + lds[2][threadIdx.x] + lds[3][threadIdx.x];
}

// K2: second pass over x (L3-hot): partial {Sa, Sa*u0, Sa*v0}, a = |g - mean|.
__global__ __launch_bounds__(256) void k2(const float* __restrict__ x,
                                          const double* __restrict__ p1,
                                          double* __restrict__ p2) {
    int img = blockIdx.x >> 5;
    int chunk = blockIdx.x & (NCH - 1);
    __shared__ double bmean;
    int lane = threadIdx.x & 63, wv = threadIdx.x >> 6;
    if (wv == 0) {
        double sg = (lane < NCH) ? p1[((size_t)img * NCH + lane) * NP1 + 0] : 0.0;
        sg = wredd(sg);
        if (lane == 0) bmean = sg / (double)NPIX;
    }
    __syncthreads();
    float mean = (float)bmean;

    const int iters = NPIX / NCH / 1024;
    size_t cb = (size_t)chunk * (NPIX / NCH);
    const float* xr = x + (size_t)img * 3 * NPIX;
    float sa = 0.0f, sax = 0.0f, say = 0.0f;
    for (int j = 0; j < iters; ++j) {
        size_t off = cb + ((size_t)j * 256 + threadIdx.x) * 4;
        float gv[4];
        gray4(xr, off, gv);
        float v = (float)(int)(off >> 9) - CTR;
        float u0 = (float)(int)(off & 511) - CTR;
#pragma unroll
        for (int u = 0; u < 4; ++u) {
            float a = fabsf(gv[u] - mean);
            sa += a;
            sax += a * (u0 + (float)u);
            say += a * v;
        }
    }
    __shared__ double lds[4][3];
    float acc[3] = {sa, sax, say};
#pragma unroll
    for (int a = 0; a < 3; ++a) {
        double s = wredd((double)acc[a]);
        if (lane == 0) lds[wv][a] = s;
    }
    __syncthreads();
    if (threadIdx.x < 3)
        p2[((size_t)img * NCH + chunk) * 3 + threadIdx.x] =
            lds[0][threadIdx.x] + lds[1][threadIdx.x] + lds[2][threadIdx.x] + lds[3][threadIdx.x];
}

// K3: finalize. One wave per image: binomial-shift raw moments to COM, scale, emit.
__global__ __launch_bounds__(64) void k3f(const double* __restrict__ p1,
                                          const double* __restrict__ p2,
                                          float* __restrict__ out) {
    int img = blockIdx.x;
    int lane = threadIdx.x;
    double M[11], B[3];
#pragma unroll
    for (int a = 0; a < 11; ++a) M[a] = 0.0;
#pragma unroll
    for (int a = 0; a < 3; ++a) B[a] = 0.0;
    if (lane < NCH) {
        size_t b = (size_t)img * NCH + lane;
#pragma unroll
        for (int a = 0; a < 11; ++a) M[a] = p1[b * NP1 + a];
#pragma unroll
        for (int a = 0; a < 3; ++a) B[a] = p2[b * 3 + a];
    }
#pragma unroll
    for (int a = 0; a < 11; ++a) M[a] = wredd(M[a]);
#pragma unroll
    for (int a = 0; a < 3; ++a) B[a] = wredd(B[a]);

    if (lane == 0) {
        const double N = (double)NPIX;
        double G00 = M[0], Sg2 = M[1];
        double G10 = M[2], G01 = M[3], G20 = M[4], G11 = M[5], G02 = M[6];
        double G30 = M[7], G21 = M[8], G12 = M[9], G03 = M[10];
        double A0 = B[0], Ax = B[1], Ay = B[2];

        double mean = G00 / N;
        double var = Sg2 / N - mean * mean;
        if (var < 0.0) var = 0.0;
        double inv_std = 1.0 / (sqrt(var) + 1e-8);

        double s_chk = A0 * inv_std;
        double dx, dy;  // cx-255.5, cy-255.5
        if (s_chk < 1e-8) { dx = 0.5; dy = 0.5; }
        else { dx = Ax / A0; dy = Ay / A0; }

        double S2 = 512.0 * (512.0 * 512.0 - 1.0) / 12.0;
        double P20 = S2 * 512.0, P02 = S2 * 512.0;

        double W00 = G00 - mean * N;
        double W10 = G10, W01 = G01;
        double W20 = G20 - mean * P20;
        double W11 = G11;
        double W02 = G02 - mean * P02;
        double W30 = G30, W21 = G21, W12 = G12, W03 = G03;

        double N00 = W00;
        double N10 = W10 - dx * W00;
        double N01 = W01 - dy * W00;
        double N20 = W20 - 2.0 * dx * W10 + dx * dx * W00;
        double N11 = W11 - dx * W01 - dy * W10 + dx * dy * W00;
        double N02 = W02 - 2.0 * dy * W01 + dy * dy * W00;
        double N30 = W30 - 3.0 * dx * W20 + 3.0 * dx * dx * W10 - dx * dx * dx * W00;
        double N21 = W21 - dy * W20 - 2.0 * dx * W11 + 2.0 * dx * dy * W10
                   + dx * dx * W01 - dx * dx * dy * W00;
        double N12 = W12 - dx * W02 - 2.0 * dy * W11 + 2.0 * dx * dy * W01
                   + dy * dy * W10 - dx * dy * dy * W00;
        double N03 = W03 - 3.0 * dy * W02 + 3.0 * dy * dy * W01 - dy * dy * dy * W00;

        double cx = CTR + dx, cy = CTR + dy;
        double mdx = fmax(cx, 511.0 - cx), mdy = fmax(cy, 511.0 - cy);
        double max_r = sqrt(mdx * mdx + mdy * mdy) + 1e-8;
        double imr = 1.0 / max_r;
        double im1 = inv_std * imr, im2 = im1 * imr, im3 = im2 * imr;
        double inv_denom = 1.0 / (max_r * max_r + 1e-8);

        double S0 = N00 * inv_std;
        double R2 = (N20 + N02) * im2;
        double C1 = N10 * im1, S1 = N01 * im1;
        double C2 = (N20 - N02) * im2, Sm2 = 2.0 * N11 * im2;
        double C3 = (N30 - 3.0 * N12) * im3, Sm3 = (3.0 * N21 - N03) * im3;
        double C31 = (N30 + N12) * im3, S31 = (N21 + N03) * im3;

        double f0 = fabs(S0) * inv_denom;
        double f1 = sqrt(C1 * C1 + S1 * S1) * inv_denom;
        double f3 = sqrt(C2 * C2 + Sm2 * Sm2) * inv_denom;
        double f4 = fabs(2.0 * R2 - S0) * inv_denom;
        double f6 = sqrt(C3 * C3 + Sm3 * Sm3) * inv_denom;
        double a31r = 3.0 * C31 - 2.0 * C1, a31i = 3.0 * S31 - 2.0 * S1;
        double f7 = sqrt(a31r * a31r + a31i * a31i) * inv_denom;

        float* o = out + (size_t)img * 20;
        o[0] = (float)f0;
        o[1] = (float)f1; o[2] = (float)f1;
        o[3] = (float)f3; o[4] = (float)f4; o[5] = (float)f3;
        o[6] = (float)f6; o[7] = (float)f7; o[8] = (float)f7; o[9] = (float)f6;
        for (int k = 10; k < 20; ++k) o[k] = 0.0f;
    }
}

extern "C" void kernel_launch(void* const* d_in, const int* in_sizes, int n_in,
                              void* d_out, int out_size, void* d_ws, size_t ws_size,
                              hipStream_t stream) {
    const float* x = (const float*)d_in[0];
    float* out = (float*)d_out;

    double* p1 = (double*)d_ws;
    double* p2 = p1 + (size_t)NIMG * NCH * NP1;

    dim3 grid(NIMG * NCH);
    k1<<<grid, 256, 0, stream>>>(x, p1);
    k2<<<grid, 256, 0, stream>>>(x, p1, p2);
    k3f<<<NIMG, 64, 0, stream>>>(p1, p2, out);
}